// Round 10
// baseline (293.716 us; speedup 1.0000x reference)
//
#include <hip/hip_runtime.h>
#include <math.h>

// EGNN: B=64 graphs x N=64 nodes, D=3, IN_NF=8, H=128, L=4 layers.
// R10: GEMM3 row-sliced (wave owns 32 rows x all 128 cols) -> phi reduce
// fully in-wave: 128->32 shuffles, 32->8 A-frag ds_reads, shphiP LDS
// round-trip + 1 barrier removed. GEMM2 stays col-sliced (agg in-wave).
// XCD-affinity swizzle kept from R9 (FETCH 14.3->6.8MB, verified).

#define NB 64
#define NN 64
#define DD 3
#define INNF 8
#define HH 128
#define LL 4
#define BNODES (NB * NN)  // 4096

typedef __attribute__((ext_vector_type(8))) short bf16x8;
typedef __attribute__((ext_vector_type(4))) float f32x4;
typedef __attribute__((ext_vector_type(4))) unsigned uint32x4;

__device__ __forceinline__ float silu_f(float v) {
    float e = __expf(-v);
    return v * __builtin_amdgcn_rcpf(1.0f + e);
}

__device__ __forceinline__ short f2bf(float v) {
    unsigned u = __builtin_bit_cast(unsigned, v);
    u += 0x7fffu + ((u >> 16) & 1u);  // RNE (finite values only)
    return (short)(u >> 16);
}

// HW packed convert: lo -> bits[15:0], hi -> bits[31:16], RNE.
__device__ __forceinline__ unsigned cvt_pk2(float lo, float hi) {
    unsigned r;
    asm("v_cvt_pk_bf16_f32 %0, %1, %2" : "=v"(r) : "v"(lo), "v"(hi));
    return r;
}

// ---------------- prep: x, x0, h = (feat*nm)@emb_w + emb_b ----------------
__global__ void prep_kernel(const float* __restrict__ xh, const float* __restrict__ nm,
                            const float* __restrict__ emb_w, const float* __restrict__ emb_b,
                            float* __restrict__ x, float* __restrict__ x0, float* __restrict__ h) {
    const int v = blockIdx.x;
    const int t = threadIdx.x;  // 128
    const float m = nm[v];
    __shared__ float f[INNF];
    if (t < INNF) f[t] = xh[v * (DD + INNF) + DD + t] * m;
    if (t < DD) {
        float c = xh[v * (DD + INNF) + t] * m;
        x[v * DD + t] = c;
        x0[v * DD + t] = c;
    }
    __syncthreads();
    float acc = emb_b[t];
#pragma unroll
    for (int k = 0; k < INNF; ++k) acc = fmaf(f[k], emb_w[k * HH + t], acc);
    h[v * HH + t] = acc;
}

// ---------------- weight prep: bf16, K-contiguous per output column ----------------
__global__ void wprep_kernel(const float* __restrict__ ew1, const float* __restrict__ ew2,
                             const float* __restrict__ cw1, const float* __restrict__ nw1,
                             const float* __restrict__ nw2,
                             short* __restrict__ ew1T, short* __restrict__ ew2T,
                             short* __restrict__ cw1T, short* __restrict__ nw1T,
                             short* __restrict__ nw2T) {
    const int l = blockIdx.x / 5, which = blockIdx.x % 5;
    if (which == 0) {
        const float* src = ew1 + (size_t)l * 258 * HH;
        short* dst = ew1T + (size_t)l * 256 * HH;
        for (int idx = threadIdx.x; idx < 256 * HH; idx += blockDim.x) {
            const int cp = idx >> 7, k = idx & 127;
            dst[cp * HH + k] = f2bf(src[(k + ((cp >> 7) << 7)) * HH + (cp & 127)]);
        }
    } else if (which == 3) {
        const float* src = nw1 + (size_t)l * 2 * HH * HH;
        short* dst = nw1T + (size_t)l * 2 * HH * HH;
        for (int idx = threadIdx.x; idx < 2 * HH * HH; idx += blockDim.x) {
            const int c = idx >> 8, k = idx & 255;
            dst[c * 256 + k] = f2bf(src[k * HH + c]);
        }
    } else {
        const float* src = (which == 1 ? ew2 : which == 2 ? cw1 : nw2) + (size_t)l * HH * HH;
        short* dst = (which == 1 ? ew2T : which == 2 ? cw1T : nw2T) + (size_t)l * HH * HH;
        for (int idx = threadIdx.x; idx < HH * HH; idx += blockDim.x) {
            const int k = idx >> 7, c = idx & 127;
            dst[c * HH + k] = f2bf(src[idx]);
        }
    }
}

// ---------------- layer-0 pq: P = h@Wr + eb1, Q = h@Wc (bf16 MFMA) ----------------
// grid 512, XCD swizzle: g = bid&63, q = (bid>>6)&3, half = bid>>8.
__global__ __launch_bounds__(256) void pq_kernel(const float* __restrict__ h,
                                                 const short* __restrict__ ew1Tl,
                                                 const float* __restrict__ eb1l,
                                                 float* __restrict__ P, float* __restrict__ Q) {
    const int gph = blockIdx.x & 63;
    const int g0n = gph * NN + ((blockIdx.x >> 6) & 3) * 16;
    const int half = blockIdx.x >> 8;
    const int t = threadIdx.x;
    const int w = t >> 6, l = t & 63, l15 = l & 15, l4 = l >> 4;
    __shared__ __align__(16) char shN[16 * 256];

    {
        const int row = t >> 4, k0 = (t & 15) * 8;
        const float* hp = h + (size_t)(g0n + row) * HH + k0;
        const float4 a = *(const float4*)hp;
        const float4 b = *(const float4*)(hp + 4);
        uint32x4 s;
        s[0] = cvt_pk2(a.x, a.y);
        s[1] = cvt_pk2(a.z, a.w);
        s[2] = cvt_pk2(b.x, b.y);
        s[3] = cvt_pk2(b.z, b.w);
        *(uint32x4*)(shN + row * 256 + ((k0 * 2) ^ ((row & 7) << 4))) = s;
    }
    __syncthreads();

    const int c0 = half * 128 + w * 32;
    f32x4 acc[2];
    acc[0] = (f32x4){0.f, 0.f, 0.f, 0.f};
    acc[1] = (f32x4){0.f, 0.f, 0.f, 0.f};
#pragma unroll
    for (int kt = 0; kt < 4; ++kt) {
        const bf16x8 af = *(const bf16x8*)(shN + l15 * 256 + (((kt * 4 + l4) * 16) ^ ((l15 & 7) << 4)));
#pragma unroll
        for (int ct2 = 0; ct2 < 2; ++ct2) {
            const bf16x8 bf = *(const bf16x8*)(ew1Tl + (size_t)(c0 + ct2 * 16 + l15) * HH + kt * 32 + l4 * 8);
            acc[ct2] = __builtin_amdgcn_mfma_f32_16x16x32_bf16(af, bf, acc[ct2], 0, 0, 0);
        }
    }
#pragma unroll
    for (int ct2 = 0; ct2 < 2; ++ct2) {
        const int cp = c0 + ct2 * 16 + l15;
        const int c = cp & 127;
        float* dst = (cp >= HH) ? Q : P;
        const float bias = (cp >= HH) ? 0.0f : eb1l[c];
#pragma unroll
        for (int reg = 0; reg < 4; ++reg) {
            const int n = g0n + l4 * 4 + reg;
            dst[(size_t)n * HH + c] = acc[ct2][reg] + bias;
        }
    }
}

// ---------------- per-layer edge kernel: TWO row-nodes per block ----------------
// grid 2048, XCD swizzle: g = bid&63, ii = bid>>6 -> bid%8 == g%8 (same XCD per graph).
__global__ __launch_bounds__(256, 4) void edge_kernel(
    const float* __restrict__ P, const float* __restrict__ Q,
    const float* __restrict__ x, const float* __restrict__ x0,
    const float* __restrict__ em,
    const float* __restrict__ ew1l,   // [258][128] (rows 256,257 used)
    const short* __restrict__ ew2T,   // [128 cols][128 k] bf16
    const float* __restrict__ eb2l,
    const short* __restrict__ cw1T,   // [128 cols][128 k] bf16
    const float* __restrict__ cb1l,
    const float* __restrict__ cw2l,
    float* __restrict__ x_out, float* __restrict__ agg) {

    const int g  = blockIdx.x & 63;   // graph -> fixed XCD (bid % 8 == g % 8)
    const int ii = blockIdx.x >> 6;   // 0..31
    const int iA = ii, iB = ii + 32;
    const int g0 = g * NN;
    const int rA = g0 + iA, rB = g0 + iB;
    const int t = threadIdx.x;       // 256
    const int w = t >> 6;
    const int l = t & 63;
    const int l15 = l & 15, l4 = l >> 4;
    const int c0 = w * 32;

    __shared__ __align__(16) char shAc[128 * 256];  // rows 0-63: node A, 64-127: node B (32 KB)
    float* shx0g  = (float*)(shAc + 2048); // overlay: used only BEFORE build writes
    __shared__ float shPA[HH], shPB[HH], shw256[HH], shw257[HH];
    __shared__ float shEb2[HH], shCb1[HH], shCw2[HH];
    __shared__ float shx[NN * 3];
    __shared__ float shradA[NN], shradB[NN], sheaA[NN], sheaB[NN], shemA[NN], shemB[NN];
    __shared__ float shcdnA[NN * 3], shcdnB[NN * 3];
    __shared__ float shphi[128];  // rows 0-63: node A, 64-127: node B

    if (t < HH) {
        shPA[t] = P[rA * HH + t];
        shPB[t] = P[rB * HH + t];
        shw256[t] = ew1l[256 * HH + t];
        shw257[t] = ew1l[257 * HH + t];
        shEb2[t] = eb2l[t];
        shCb1[t] = cb1l[t];
        shCw2[t] = cw2l[t];
    }
    if (t < NN * 3) {
        shx[t] = x[g0 * 3 + t];
        shx0g[t] = x0[g0 * 3 + t];
    }
    __syncthreads();
    if (t < 2 * NN) {  // wave0: node A geometry, wave1: node B (wave-uniform)
        const int j = t & 63;
        const bool isB = (t >= NN);
        const int ni = isB ? iB : iA;
        float dx = shx[ni * 3 + 0] - shx[j * 3 + 0];
        float dy = shx[ni * 3 + 1] - shx[j * 3 + 1];
        float dz = shx[ni * 3 + 2] - shx[j * 3 + 2];
        float rad = dx * dx + dy * dy + dz * dz;
        float inv = 1.0f / (sqrtf(rad + 1e-8f) + 1.0f);
        float ex = shx0g[ni * 3 + 0] - shx0g[j * 3 + 0];
        float ey = shx0g[ni * 3 + 1] - shx0g[j * 3 + 1];
        float ez = shx0g[ni * 3 + 2] - shx0g[j * 3 + 2];
        float ea = ex * ex + ey * ey + ez * ez;
        float* radp = isB ? shradB : shradA;
        float* eap  = isB ? sheaB : sheaA;
        float* emp  = isB ? shemB : shemA;
        float* cdnp = isB ? shcdnB : shcdnA;
        radp[j] = rad;
        eap[j] = ea;
        emp[j] = em[(isB ? rB : rA) * NN + j];
        cdnp[j * 3 + 0] = dx * inv;
        cdnp[j * 3 + 1] = dy * inv;
        cdnp[j * 3 + 2] = dz * inv;
    }
    __syncthreads();  // geometry done; shx0g overlay now dead

    // ---- build t1 rows for BOTH nodes (Q row loaded once, used twice) ----
    {
        const int j = t >> 2;  // 0..63
        const float radA = shradA[j], eaA = sheaA[j];
        const float radB = shradB[j], eaB = sheaB[j];
        const int xr = (j & 7) << 4;
#pragma unroll
        for (int p = 0; p < 4; ++p) {
            const int k0 = (t & 3) * 8 + p * 32;
            const float4 qa = *(const float4*)(Q + (size_t)(g0 + j) * HH + k0);
            const float4 qb = *(const float4*)(Q + (size_t)(g0 + j) * HH + k0 + 4);
            const float qv[8] = {qa.x, qa.y, qa.z, qa.w, qb.x, qb.y, qb.z, qb.w};
            uint32x4 sA, sB;
#pragma unroll
            for (int u2 = 0; u2 < 4; ++u2) {
                const int ka = k0 + 2 * u2, kb = ka + 1;
                const float w2a = shw256[ka], w3a = shw257[ka];
                const float w2b = shw256[kb], w3b = shw257[kb];
                float vA0 = silu_f(shPA[ka] + qv[2 * u2] + radA * w2a + eaA * w3a);
                float vA1 = silu_f(shPA[kb] + qv[2 * u2 + 1] + radA * w2b + eaA * w3b);
                float vB0 = silu_f(shPB[ka] + qv[2 * u2] + radB * w2a + eaB * w3a);
                float vB1 = silu_f(shPB[kb] + qv[2 * u2 + 1] + radB * w2b + eaB * w3b);
                sA[u2] = cvt_pk2(vA0, vA1);
                sB[u2] = cvt_pk2(vB0, vB1);
            }
            const int off = (k0 * 2) ^ xr;
            *(uint32x4*)(shAc + j * 256 + off) = sA;
            *(uint32x4*)(shAc + (j + 64) * 256 + off) = sB;  // (j+64)&7 == j&7
        }
    }
    __syncthreads();

    // ---- GEMM2: m = silu(t1 @ ew2 + eb2) * em  (col-sliced, B double-buffered) ----
    f32x4 acc[8][2];
#pragma unroll
    for (int rt = 0; rt < 8; ++rt) {
        acc[rt][0] = (f32x4){0.f, 0.f, 0.f, 0.f};
        acc[rt][1] = (f32x4){0.f, 0.f, 0.f, 0.f};
    }
    {
        const short* B2 = ew2T + (size_t)(c0 + l15) * HH + l4 * 8;
        bf16x8 bcur[2], bnxt[2];
        bcur[0] = *(const bf16x8*)(B2);
        bcur[1] = *(const bf16x8*)(B2 + 16 * HH);
#pragma unroll
        for (int kt = 0; kt < 4; ++kt) {
            if (kt < 3) {
                bnxt[0] = *(const bf16x8*)(B2 + (kt + 1) * 32);
                bnxt[1] = *(const bf16x8*)(B2 + 16 * HH + (kt + 1) * 32);
            }
            bf16x8 af[8];
#pragma unroll
            for (int rt = 0; rt < 8; ++rt) {
                const int row = rt * 16 + l15;
                af[rt] = *(const bf16x8*)(shAc + row * 256 + (((kt * 4 + l4) * 16) ^ ((row & 7) << 4)));
            }
#pragma unroll
            for (int rt = 0; rt < 8; ++rt) {
                acc[rt][0] = __builtin_amdgcn_mfma_f32_16x16x32_bf16(af[rt], bcur[0], acc[rt][0], 0, 0, 0);
                acc[rt][1] = __builtin_amdgcn_mfma_f32_16x16x32_bf16(af[rt], bcur[1], acc[rt][1], 0, 0, 0);
            }
            bcur[0] = bnxt[0];
            bcur[1] = bnxt[1];
        }
    }
    __syncthreads();  // GEMM2 A-reads done before m overwrites shAc

    // epilogue: m = silu(acc+eb2)*em -> shAc; agg in-wave for both nodes
#pragma unroll
    for (int ct2 = 0; ct2 < 2; ++ct2) {
        const int c = c0 + ct2 * 16 + l15;
        const float b = shEb2[c];
        float paggA = 0.0f, paggB = 0.0f;
#pragma unroll
        for (int rt = 0; rt < 8; ++rt) {
            const int rbase = rt * 16 + l4 * 4;
            float v[4];
#pragma unroll
            for (int reg = 0; reg < 4; ++reg) {
                const int row = rbase + reg;
                const float emv = (rt < 4) ? shemA[row] : shemB[row - 64];
                v[reg] = silu_f(acc[rt][ct2][reg] + b) * emv;
                if (rt < 4) paggA += v[reg]; else paggB += v[reg];
            }
            const unsigned wlo = cvt_pk2(v[0], v[1]);
            const unsigned whi = cvt_pk2(v[2], v[3]);
            const int cx = c * 2;
#pragma unroll
            for (int reg = 0; reg < 4; ++reg) {
                const int row = rbase + reg;
                const unsigned wv = (reg < 2) ? wlo : whi;
                const short sv = (reg & 1) ? (short)(wv >> 16) : (short)(wv & 0xffff);
                *(short*)(shAc + row * 256 + (cx ^ ((row & 7) << 4))) = sv;
            }
        }
        paggA += __shfl_xor(paggA, 16);
        paggA += __shfl_xor(paggA, 32);
        paggB += __shfl_xor(paggB, 16);
        paggB += __shfl_xor(paggB, 32);
        if (l4 == 0) {
            agg[rA * HH + c] = paggA;
            agg[rB * HH + c] = paggB;
        }
    }
    __syncthreads();  // m complete before GEMM3 A reads

    // ---- GEMM3 (row-sliced): wave w owns rows [w*32, w*32+32), ALL 128 cols ----
    // acc reused as acc3[ct 0..7][rt 0..1]
#pragma unroll
    for (int ct = 0; ct < 8; ++ct) {
        acc[ct][0] = (f32x4){0.f, 0.f, 0.f, 0.f};
        acc[ct][1] = (f32x4){0.f, 0.f, 0.f, 0.f};
    }
    {
        const int rb = w * 32;
#pragma unroll
        for (int kt = 0; kt < 4; ++kt) {
            bf16x8 af[2];
#pragma unroll
            for (int rt = 0; rt < 2; ++rt) {
                const int row = rb + rt * 16 + l15;
                af[rt] = *(const bf16x8*)(shAc + row * 256 + (((kt * 4 + l4) * 16) ^ ((row & 7) << 4)));
            }
#pragma unroll
            for (int ct = 0; ct < 8; ++ct) {
                const bf16x8 bf = *(const bf16x8*)(cw1T + (size_t)(ct * 16 + l15) * HH + kt * 32 + l4 * 8);
                acc[ct][0] = __builtin_amdgcn_mfma_f32_16x16x32_bf16(af[0], bf, acc[ct][0], 0, 0, 0);
                acc[ct][1] = __builtin_amdgcn_mfma_f32_16x16x32_bf16(af[1], bf, acc[ct][1], 0, 0, 0);
            }
        }
    }

    // epilogue: phi fully in-wave (each lane sums its 8 cols, reduce over l15)
    {
        float pp[2][4];
#pragma unroll
        for (int rt = 0; rt < 2; ++rt)
#pragma unroll
            for (int reg = 0; reg < 4; ++reg) pp[rt][reg] = 0.0f;
#pragma unroll
        for (int ct = 0; ct < 8; ++ct) {
            const int c = ct * 16 + l15;
            const float cb = shCb1[c], cw = shCw2[c];
#pragma unroll
            for (int rt = 0; rt < 2; ++rt) {
#pragma unroll
                for (int reg = 0; reg < 4; ++reg) {
                    float v = silu_f(acc[ct][rt][reg] + cb);
                    pp[rt][reg] = fmaf(v, cw, pp[rt][reg]);
                }
            }
        }
#pragma unroll
        for (int off = 8; off >= 1; off >>= 1) {
#pragma unroll
            for (int rt = 0; rt < 2; ++rt)
#pragma unroll
                for (int reg = 0; reg < 4; ++reg) pp[rt][reg] += __shfl_xor(pp[rt][reg], off);
        }
        if (l15 == 0) {
#pragma unroll
            for (int rt = 0; rt < 2; ++rt)
#pragma unroll
                for (int reg = 0; reg < 4; ++reg)
                    shphi[w * 32 + rt * 16 + l4 * 4 + reg] = pp[rt][reg];
        }
    }
    __syncthreads();

    // x_out for both nodes (3 waves, one per coord; two sequential reductions)
    if (t < 192) {
        const int q = t >> 6, j = t & 63;
        float vA = shcdnA[j * 3 + q] * shphi[j] * shemA[j];
        float vB = shcdnB[j * 3 + q] * shphi[64 + j] * shemB[j];
#pragma unroll
        for (int off = 32; off >= 1; off >>= 1) {
            vA += __shfl_xor(vA, off);
            vB += __shfl_xor(vB, off);
        }
        if (j == 0) {
            x_out[rA * 3 + q] = shx[iA * 3 + q] + vA;
            x_out[rB * 3 + q] = shx[iB * 3 + q] + vB;
        }
    }
}

// ---------------- fused: node update (in place) + NEXT layer's P,Q ----------------
// grid 256, XCD swizzle: g = bid&63, quarter = bid>>6 -> writer XCD == reader XCD.
__global__ __launch_bounds__(256) void nodepq_kernel(
    float* __restrict__ h, const float* __restrict__ agg, const float* __restrict__ nm,
    const short* __restrict__ nw1Tl, const float* __restrict__ nb1l,
    const short* __restrict__ nw2Tl, const float* __restrict__ nb2l,
    const short* __restrict__ ew1Tn, const float* __restrict__ eb1n,  // next layer
    float* __restrict__ P, float* __restrict__ Q, int do_pq) {
    const int g0n = (blockIdx.x & 63) * NN + (blockIdx.x >> 6) * 16;
    const int t = threadIdx.x;
    const int w = t >> 6, l = t & 63, l15 = l & 15, l4 = l >> 4;
    __shared__ __align__(16) char shN[16 * 512];  // [16 rows][256 bf16] = [h|agg], swizzled
    __shared__ __align__(16) char shT[16 * 256];  // [16 rows][128 bf16], swizzled
    char* shH = shN;  // reuse (dead after first GEMM) for new-h staging [16][128]

    {
        const int row = t >> 4, k0 = (t & 15) * 16;
        const float* src = (k0 < HH) ? (h + (size_t)(g0n + row) * HH + k0)
                                     : (agg + (size_t)(g0n + row) * HH + (k0 - HH));
        const float4 a = *(const float4*)src;
        const float4 b = *(const float4*)(src + 4);
        const float4 c = *(const float4*)(src + 8);
        const float4 d = *(const float4*)(src + 12);
        uint32x4 s0, s1;
        s0[0] = cvt_pk2(a.x, a.y); s0[1] = cvt_pk2(a.z, a.w);
        s0[2] = cvt_pk2(b.x, b.y); s0[3] = cvt_pk2(b.z, b.w);
        s1[0] = cvt_pk2(c.x, c.y); s1[1] = cvt_pk2(c.z, c.w);
        s1[2] = cvt_pk2(d.x, d.y); s1[3] = cvt_pk2(d.z, d.w);
        const int xr = (row & 7) << 4;
        *(uint32x4*)(shN + row * 512 + ((k0 * 2) ^ xr)) = s0;
        *(uint32x4*)(shN + row * 512 + ((k0 * 2 + 16) ^ xr)) = s1;
    }
    __syncthreads();

    const int c0 = w * 32;
    f32x4 acc[2];
    acc[0] = (f32x4){0.f, 0.f, 0.f, 0.f};
    acc[1] = (f32x4){0.f, 0.f, 0.f, 0.f};
#pragma unroll
    for (int kt = 0; kt < 8; ++kt) {
        const bf16x8 af = *(const bf16x8*)(shN + l15 * 512 + (((kt * 4 + l4) * 16) ^ ((l15 & 7) << 4)));
#pragma unroll
        for (int ct2 = 0; ct2 < 2; ++ct2) {
            const bf16x8 bf = *(const bf16x8*)(nw1Tl + (size_t)(c0 + ct2 * 16 + l15) * 256 + kt * 32 + l4 * 8);
            acc[ct2] = __builtin_amdgcn_mfma_f32_16x16x32_bf16(af, bf, acc[ct2], 0, 0, 0);
        }
    }
    __syncthreads();  // all shN reads done (shH overwrite below must not race)
#pragma unroll
    for (int ct2 = 0; ct2 < 2; ++ct2) {
        const int c = c0 + ct2 * 16 + l15;
        const float b = nb1l[c];
        float v[4];
#pragma unroll
        for (int reg = 0; reg < 4; ++reg) v[reg] = silu_f(acc[ct2][reg] + b);
        const unsigned wlo = cvt_pk2(v[0], v[1]);
        const unsigned whi = cvt_pk2(v[2], v[3]);
#pragma unroll
        for (int reg = 0; reg < 4; ++reg) {
            const int row = l4 * 4 + reg;
            const unsigned wv = (reg < 2) ? wlo : whi;
            const short sv = (reg & 1) ? (short)(wv >> 16) : (short)(wv & 0xffff);
            *(short*)(shT + row * 256 + ((c * 2) ^ ((row & 7) << 4))) = sv;
        }
    }
    __syncthreads();

    acc[0] = (f32x4){0.f, 0.f, 0.f, 0.f};
    acc[1] = (f32x4){0.f, 0.f, 0.f, 0.f};
#pragma unroll
    for (int kt = 0; kt < 4; ++kt) {
        const bf16x8 af = *(const bf16x8*)(shT + l15 * 256 + (((kt * 4 + l4) * 16) ^ ((l15 & 7) << 4)));
#pragma unroll
        for (int ct2 = 0; ct2 < 2; ++ct2) {
            const bf16x8 bf = *(const bf16x8*)(nw2Tl + (size_t)(c0 + ct2 * 16 + l15) * HH + kt * 32 + l4 * 8);
            acc[ct2] = __builtin_amdgcn_mfma_f32_16x16x32_bf16(af, bf, acc[ct2], 0, 0, 0);
        }
    }
    // h' = (h + mlp + b)*nm : write global, stage bf16 into shH for pq
    float hn[2][4];
#pragma unroll
    for (int ct2 = 0; ct2 < 2; ++ct2) {
        const int c = c0 + ct2 * 16 + l15;
        const float b = nb2l[c];
#pragma unroll
        for (int reg = 0; reg < 4; ++reg) {
            const int n = g0n + l4 * 4 + reg;
            const float hv = h[(size_t)n * HH + c];
            hn[ct2][reg] = (hv + acc[ct2][reg] + b) * nm[n];
            h[(size_t)n * HH + c] = hn[ct2][reg];
        }
    }
    if (!do_pq) return;

#pragma unroll
    for (int ct2 = 0; ct2 < 2; ++ct2) {
        const int c = c0 + ct2 * 16 + l15;
        const unsigned wlo = cvt_pk2(hn[ct2][0], hn[ct2][1]);
        const unsigned whi = cvt_pk2(hn[ct2][2], hn[ct2][3]);
#pragma unroll
        for (int reg = 0; reg < 4; ++reg) {
            const int row = l4 * 4 + reg;
            const unsigned wv = (reg < 2) ? wlo : whi;
            const short sv = (reg & 1) ? (short)(wv >> 16) : (short)(wv & 0xffff);
            *(short*)(shH + row * 256 + ((c * 2) ^ ((row & 7) << 4))) = sv;
        }
    }
    __syncthreads();

    // pq GEMM: 256 output cols; wave w covers c' = half*128 + [c0, c0+32)
    f32x4 pacc[2][2];
#pragma unroll
    for (int half = 0; half < 2; ++half) {
        pacc[half][0] = (f32x4){0.f, 0.f, 0.f, 0.f};
        pacc[half][1] = (f32x4){0.f, 0.f, 0.f, 0.f};
    }
#pragma unroll
    for (int kt = 0; kt < 4; ++kt) {
        const bf16x8 af = *(const bf16x8*)(shH + l15 * 256 + (((kt * 4 + l4) * 16) ^ ((l15 & 7) << 4)));
#pragma unroll
        for (int half = 0; half < 2; ++half) {
#pragma unroll
            for (int ct2 = 0; ct2 < 2; ++ct2) {
                const bf16x8 bf = *(const bf16x8*)(ew1Tn + (size_t)(half * 128 + c0 + ct2 * 16 + l15) * HH + kt * 32 + l4 * 8);
                pacc[half][ct2] = __builtin_amdgcn_mfma_f32_16x16x32_bf16(af, bf, pacc[half][ct2], 0, 0, 0);
            }
        }
    }
#pragma unroll
    for (int half = 0; half < 2; ++half) {
#pragma unroll
        for (int ct2 = 0; ct2 < 2; ++ct2) {
            const int cp = half * 128 + c0 + ct2 * 16 + l15;
            const int c = cp & 127;
            float* dst = (cp >= HH) ? Q : P;
            const float bias = (cp >= HH) ? 0.0f : eb1n[c];
#pragma unroll
            for (int reg = 0; reg < 4; ++reg) {
                const int n = g0n + l4 * 4 + reg;
                dst[(size_t)n * HH + c] = pacc[half][ct2][reg] + bias;
            }
        }
    }
}

// ---------------- output: per-graph mean of (h@out_w + out_b)*nm ----------------
__global__ void out_kernel(const float* __restrict__ h, const float* __restrict__ nm,
                           const float* __restrict__ ow, const float* __restrict__ ob,
                           float* __restrict__ out) {
    const int b = blockIdx.x;
    const int n = threadIdx.x;  // 64
    const int v = b * NN + n;
    float acc = 0.0f;
#pragma unroll 8
    for (int c = 0; c < HH; ++c) acc = fmaf(h[v * HH + c], ow[c], acc);
    acc = (acc + ob[0]) * nm[v];
#pragma unroll
    for (int off = 32; off >= 1; off >>= 1) acc += __shfl_xor(acc, off);
    if (n == 0) out[b] = acc * (1.0f / (float)NN);
}

extern "C" void kernel_launch(void* const* d_in, const int* in_sizes, int n_in,
                              void* d_out, int out_size, void* d_ws, size_t ws_size,
                              hipStream_t stream) {
    const float* xh    = (const float*)d_in[0];
    const float* nmask = (const float*)d_in[1];
    const float* emask = (const float*)d_in[2];
    const float* emb_w = (const float*)d_in[3];
    const float* emb_b = (const float*)d_in[4];
    const float* out_w = (const float*)d_in[5];
    const float* out_b = (const float*)d_in[6];
    const float* ew1   = (const float*)d_in[7];
    const float* eb1   = (const float*)d_in[8];
    const float* ew2   = (const float*)d_in[9];
    const float* eb2   = (const float*)d_in[10];
    const float* nw1   = (const float*)d_in[11];
    const float* nb1   = (const float*)d_in[12];
    const float* nw2   = (const float*)d_in[13];
    const float* nb2   = (const float*)d_in[14];
    const float* cw1   = (const float*)d_in[15];
    const float* cb1   = (const float*)d_in[16];
    const float* cw2   = (const float*)d_in[17];

    float* ws  = (float*)d_ws;
    float* xA  = ws;                    // [4096*3]
    float* xB  = xA + BNODES * 3;       // [4096*3]
    float* x0  = xB + BNODES * 3;       // [4096*3]
    float* h   = x0 + BNODES * 3;       // [4096*128]
    float* Pb  = h + BNODES * HH;       // [4096*128]
    float* Qb  = Pb + BNODES * HH;      // [4096*128]
    float* agg = Qb + BNODES * HH;      // [4096*128]
    short* ew2T = (short*)(agg + BNODES * HH);  // [4][128*128] bf16
    short* cw1T = ew2T + LL * HH * HH;          // [4][128*128] bf16
    short* ew1T = cw1T + LL * HH * HH;          // [4][256*128] bf16
    short* nw1T = ew1T + LL * 256 * HH;         // [4][128*256] bf16
    short* nw2T = nw1T + LL * 256 * HH;         // [4][128*128] bf16

    prep_kernel<<<BNODES, HH, 0, stream>>>(xh, nmask, emb_w, emb_b, xA, x0, h);
    wprep_kernel<<<5 * LL, 256, 0, stream>>>(ew1, ew2, cw1, nw1, nw2,
                                             ew1T, ew2T, cw1T, nw1T, nw2T);

    pq_kernel<<<512, 256, 0, stream>>>(h, ew1T, eb1, Pb, Qb);

    float* xc = xA;
    float* xn = xB;
    for (int l = 0; l < LL; ++l) {
        const float* ew1l = ew1 + (size_t)l * 258 * HH;
        edge_kernel<<<BNODES / 2, 256, 0, stream>>>(Pb, Qb, xc, x0, emask, ew1l,
                                                    ew2T + (size_t)l * HH * HH, eb2 + l * HH,
                                                    cw1T + (size_t)l * HH * HH, cb1 + l * HH,
                                                    cw2 + (size_t)l * HH, xn, agg);
        const int do_pq = (l + 1 < LL) ? 1 : 0;
        const int ln = do_pq ? (l + 1) : 0;
        nodepq_kernel<<<256, 256, 0, stream>>>(h, agg, nmask,
                                               nw1T + (size_t)l * 2 * HH * HH, nb1 + l * HH,
                                               nw2T + (size_t)l * HH * HH, nb2 + l * HH,
                                               ew1T + (size_t)ln * 256 * HH, eb1 + ln * HH,
                                               Pb, Qb, do_pq);
        float* tmp = xc; xc = xn; xn = tmp;
    }

    out_kernel<<<NB, NN, 0, stream>>>(h, nmask, out_w, out_b, (float*)d_out);
}

// Round 11
// 255.561 us; speedup vs baseline: 1.1493x; 1.1493x over previous
//
#include <hip/hip_runtime.h>
#include <math.h>

// EGNN: B=64 graphs x N=64 nodes, D=3, IN_NF=8, H=128, L=4 layers.
// R11: revert to R9 structure (col-sliced GEMM2+GEMM3, best measured) after
// R10's row-sliced GEMM3 regression (4x B-traffic, vmem-serialized).
// Adds: (1) build-phase Q loads issued 8-deep up front (vmem pipelining);
// (2) s_setprio(1) around MFMA clusters (4 blocks/CU at different phases).

#define NB 64
#define NN 64
#define DD 3
#define INNF 8
#define HH 128
#define LL 4
#define BNODES (NB * NN)  // 4096

typedef __attribute__((ext_vector_type(8))) short bf16x8;
typedef __attribute__((ext_vector_type(4))) float f32x4;
typedef __attribute__((ext_vector_type(4))) unsigned uint32x4;

__device__ __forceinline__ float silu_f(float v) {
    float e = __expf(-v);
    return v * __builtin_amdgcn_rcpf(1.0f + e);
}

__device__ __forceinline__ short f2bf(float v) {
    unsigned u = __builtin_bit_cast(unsigned, v);
    u += 0x7fffu + ((u >> 16) & 1u);  // RNE (finite values only)
    return (short)(u >> 16);
}

// HW packed convert: lo -> bits[15:0], hi -> bits[31:16], RNE.
__device__ __forceinline__ unsigned cvt_pk2(float lo, float hi) {
    unsigned r;
    asm("v_cvt_pk_bf16_f32 %0, %1, %2" : "=v"(r) : "v"(lo), "v"(hi));
    return r;
}

// ---------------- prep: x, x0, h = (feat*nm)@emb_w + emb_b ----------------
__global__ void prep_kernel(const float* __restrict__ xh, const float* __restrict__ nm,
                            const float* __restrict__ emb_w, const float* __restrict__ emb_b,
                            float* __restrict__ x, float* __restrict__ x0, float* __restrict__ h) {
    const int v = blockIdx.x;
    const int t = threadIdx.x;  // 128
    const float m = nm[v];
    __shared__ float f[INNF];
    if (t < INNF) f[t] = xh[v * (DD + INNF) + DD + t] * m;
    if (t < DD) {
        float c = xh[v * (DD + INNF) + t] * m;
        x[v * DD + t] = c;
        x0[v * DD + t] = c;
    }
    __syncthreads();
    float acc = emb_b[t];
#pragma unroll
    for (int k = 0; k < INNF; ++k) acc = fmaf(f[k], emb_w[k * HH + t], acc);
    h[v * HH + t] = acc;
}

// ---------------- weight prep: bf16, K-contiguous per output column ----------------
__global__ void wprep_kernel(const float* __restrict__ ew1, const float* __restrict__ ew2,
                             const float* __restrict__ cw1, const float* __restrict__ nw1,
                             const float* __restrict__ nw2,
                             short* __restrict__ ew1T, short* __restrict__ ew2T,
                             short* __restrict__ cw1T, short* __restrict__ nw1T,
                             short* __restrict__ nw2T) {
    const int l = blockIdx.x / 5, which = blockIdx.x % 5;
    if (which == 0) {
        const float* src = ew1 + (size_t)l * 258 * HH;
        short* dst = ew1T + (size_t)l * 256 * HH;
        for (int idx = threadIdx.x; idx < 256 * HH; idx += blockDim.x) {
            const int cp = idx >> 7, k = idx & 127;
            dst[cp * HH + k] = f2bf(src[(k + ((cp >> 7) << 7)) * HH + (cp & 127)]);
        }
    } else if (which == 3) {
        const float* src = nw1 + (size_t)l * 2 * HH * HH;
        short* dst = nw1T + (size_t)l * 2 * HH * HH;
        for (int idx = threadIdx.x; idx < 2 * HH * HH; idx += blockDim.x) {
            const int c = idx >> 8, k = idx & 255;
            dst[c * 256 + k] = f2bf(src[k * HH + c]);
        }
    } else {
        const float* src = (which == 1 ? ew2 : which == 2 ? cw1 : nw2) + (size_t)l * HH * HH;
        short* dst = (which == 1 ? ew2T : which == 2 ? cw1T : nw2T) + (size_t)l * HH * HH;
        for (int idx = threadIdx.x; idx < HH * HH; idx += blockDim.x) {
            const int k = idx >> 7, c = idx & 127;
            dst[c * HH + k] = f2bf(src[idx]);
        }
    }
}

// ---------------- layer-0 pq: P = h@Wr + eb1, Q = h@Wc (bf16 MFMA) ----------------
// grid 512, XCD swizzle: g = bid&63, q = (bid>>6)&3, half = bid>>8.
__global__ __launch_bounds__(256) void pq_kernel(const float* __restrict__ h,
                                                 const short* __restrict__ ew1Tl,
                                                 const float* __restrict__ eb1l,
                                                 float* __restrict__ P, float* __restrict__ Q) {
    const int gph = blockIdx.x & 63;
    const int g0n = gph * NN + ((blockIdx.x >> 6) & 3) * 16;
    const int half = blockIdx.x >> 8;
    const int t = threadIdx.x;
    const int w = t >> 6, l = t & 63, l15 = l & 15, l4 = l >> 4;
    __shared__ __align__(16) char shN[16 * 256];

    {
        const int row = t >> 4, k0 = (t & 15) * 8;
        const float* hp = h + (size_t)(g0n + row) * HH + k0;
        const float4 a = *(const float4*)hp;
        const float4 b = *(const float4*)(hp + 4);
        uint32x4 s;
        s[0] = cvt_pk2(a.x, a.y);
        s[1] = cvt_pk2(a.z, a.w);
        s[2] = cvt_pk2(b.x, b.y);
        s[3] = cvt_pk2(b.z, b.w);
        *(uint32x4*)(shN + row * 256 + ((k0 * 2) ^ ((row & 7) << 4))) = s;
    }
    __syncthreads();

    const int c0 = half * 128 + w * 32;
    f32x4 acc[2];
    acc[0] = (f32x4){0.f, 0.f, 0.f, 0.f};
    acc[1] = (f32x4){0.f, 0.f, 0.f, 0.f};
#pragma unroll
    for (int kt = 0; kt < 4; ++kt) {
        const bf16x8 af = *(const bf16x8*)(shN + l15 * 256 + (((kt * 4 + l4) * 16) ^ ((l15 & 7) << 4)));
#pragma unroll
        for (int ct2 = 0; ct2 < 2; ++ct2) {
            const bf16x8 bf = *(const bf16x8*)(ew1Tl + (size_t)(c0 + ct2 * 16 + l15) * HH + kt * 32 + l4 * 8);
            acc[ct2] = __builtin_amdgcn_mfma_f32_16x16x32_bf16(af, bf, acc[ct2], 0, 0, 0);
        }
    }
#pragma unroll
    for (int ct2 = 0; ct2 < 2; ++ct2) {
        const int cp = c0 + ct2 * 16 + l15;
        const int c = cp & 127;
        float* dst = (cp >= HH) ? Q : P;
        const float bias = (cp >= HH) ? 0.0f : eb1l[c];
#pragma unroll
        for (int reg = 0; reg < 4; ++reg) {
            const int n = g0n + l4 * 4 + reg;
            dst[(size_t)n * HH + c] = acc[ct2][reg] + bias;
        }
    }
}

// ---------------- per-layer edge kernel: TWO row-nodes per block ----------------
// grid 2048, XCD swizzle: g = bid&63, ii = bid>>6 -> bid%8 == g%8 (same XCD per graph).
__global__ __launch_bounds__(256, 4) void edge_kernel(
    const float* __restrict__ P, const float* __restrict__ Q,
    const float* __restrict__ x, const float* __restrict__ x0,
    const float* __restrict__ em,
    const float* __restrict__ ew1l,   // [258][128] (rows 256,257 used)
    const short* __restrict__ ew2T,   // [128 cols][128 k] bf16
    const float* __restrict__ eb2l,
    const short* __restrict__ cw1T,   // [128 cols][128 k] bf16
    const float* __restrict__ cb1l,
    const float* __restrict__ cw2l,
    float* __restrict__ x_out, float* __restrict__ agg) {

    const int g  = blockIdx.x & 63;   // graph -> fixed XCD (bid % 8 == g % 8)
    const int ii = blockIdx.x >> 6;   // 0..31
    const int iA = ii, iB = ii + 32;
    const int g0 = g * NN;
    const int rA = g0 + iA, rB = g0 + iB;
    const int t = threadIdx.x;       // 256
    const int w = t >> 6;
    const int l = t & 63;
    const int l15 = l & 15, l4 = l >> 4;
    const int c0 = w * 32;

    __shared__ __align__(16) char shAc[128 * 256];  // rows 0-63: node A, 64-127: node B (32 KB)
    float* shphiP = (float*)(shAc);        // overlay: used only AFTER GEMM3 reads
    float* shx0g  = (float*)(shAc + 2048); // overlay: used only BEFORE build writes
    __shared__ float shPA[HH], shPB[HH], shw256[HH], shw257[HH];
    __shared__ float shEb2[HH], shCb1[HH], shCw2[HH];
    __shared__ float shx[NN * 3];
    __shared__ float shradA[NN], shradB[NN], sheaA[NN], sheaB[NN], shemA[NN], shemB[NN];
    __shared__ float shcdnA[NN * 3], shcdnB[NN * 3];

    if (t < HH) {
        shPA[t] = P[rA * HH + t];
        shPB[t] = P[rB * HH + t];
        shw256[t] = ew1l[256 * HH + t];
        shw257[t] = ew1l[257 * HH + t];
        shEb2[t] = eb2l[t];
        shCb1[t] = cb1l[t];
        shCw2[t] = cw2l[t];
    }
    if (t < NN * 3) {
        shx[t] = x[g0 * 3 + t];
        shx0g[t] = x0[g0 * 3 + t];
    }
    __syncthreads();
    if (t < 2 * NN) {  // wave0: node A geometry, wave1: node B (wave-uniform)
        const int j = t & 63;
        const bool isB = (t >= NN);
        const int ni = isB ? iB : iA;
        float dx = shx[ni * 3 + 0] - shx[j * 3 + 0];
        float dy = shx[ni * 3 + 1] - shx[j * 3 + 1];
        float dz = shx[ni * 3 + 2] - shx[j * 3 + 2];
        float rad = dx * dx + dy * dy + dz * dz;
        float inv = 1.0f / (sqrtf(rad + 1e-8f) + 1.0f);
        float ex = shx0g[ni * 3 + 0] - shx0g[j * 3 + 0];
        float ey = shx0g[ni * 3 + 1] - shx0g[j * 3 + 1];
        float ez = shx0g[ni * 3 + 2] - shx0g[j * 3 + 2];
        float ea = ex * ex + ey * ey + ez * ez;
        float* radp = isB ? shradB : shradA;
        float* eap  = isB ? sheaB : sheaA;
        float* emp  = isB ? shemB : shemA;
        float* cdnp = isB ? shcdnB : shcdnA;
        radp[j] = rad;
        eap[j] = ea;
        emp[j] = em[(isB ? rB : rA) * NN + j];
        cdnp[j * 3 + 0] = dx * inv;
        cdnp[j * 3 + 1] = dy * inv;
        cdnp[j * 3 + 2] = dz * inv;
    }
    __syncthreads();  // geometry done; shx0g overlay now dead

    // ---- build t1 rows for BOTH nodes (Q loads issued 8-deep up front) ----
    {
        const int j = t >> 2;  // 0..63
        const float radA = shradA[j], eaA = sheaA[j];
        const float radB = shradB[j], eaB = sheaB[j];
        const int xr = (j & 7) << 4;
        float4 qbuf[8];
#pragma unroll
        for (int p = 0; p < 4; ++p) {
            const int k0 = (t & 3) * 8 + p * 32;
            qbuf[2 * p]     = *(const float4*)(Q + (size_t)(g0 + j) * HH + k0);
            qbuf[2 * p + 1] = *(const float4*)(Q + (size_t)(g0 + j) * HH + k0 + 4);
        }
#pragma unroll
        for (int p = 0; p < 4; ++p) {
            const int k0 = (t & 3) * 8 + p * 32;
            const float4 qa = qbuf[2 * p];
            const float4 qb = qbuf[2 * p + 1];
            const float qv[8] = {qa.x, qa.y, qa.z, qa.w, qb.x, qb.y, qb.z, qb.w};
            uint32x4 sA, sB;
#pragma unroll
            for (int u2 = 0; u2 < 4; ++u2) {
                const int ka = k0 + 2 * u2, kb = ka + 1;
                const float w2a = shw256[ka], w3a = shw257[ka];
                const float w2b = shw256[kb], w3b = shw257[kb];
                float vA0 = silu_f(shPA[ka] + qv[2 * u2] + radA * w2a + eaA * w3a);
                float vA1 = silu_f(shPA[kb] + qv[2 * u2 + 1] + radA * w2b + eaA * w3b);
                float vB0 = silu_f(shPB[ka] + qv[2 * u2] + radB * w2a + eaB * w3a);
                float vB1 = silu_f(shPB[kb] + qv[2 * u2 + 1] + radB * w2b + eaB * w3b);
                sA[u2] = cvt_pk2(vA0, vA1);
                sB[u2] = cvt_pk2(vB0, vB1);
            }
            const int off = (k0 * 2) ^ xr;
            *(uint32x4*)(shAc + j * 256 + off) = sA;
            *(uint32x4*)(shAc + (j + 64) * 256 + off) = sB;  // (j+64)&7 == j&7
        }
    }
    __syncthreads();

    // ---- GEMM2: m = silu(t1 @ ew2 + eb2) * em  (col-sliced, B double-buffered) ----
    f32x4 acc[8][2];
#pragma unroll
    for (int rt = 0; rt < 8; ++rt) {
        acc[rt][0] = (f32x4){0.f, 0.f, 0.f, 0.f};
        acc[rt][1] = (f32x4){0.f, 0.f, 0.f, 0.f};
    }
    {
        const short* B2 = ew2T + (size_t)(c0 + l15) * HH + l4 * 8;
        bf16x8 bcur[2], bnxt[2];
        bcur[0] = *(const bf16x8*)(B2);
        bcur[1] = *(const bf16x8*)(B2 + 16 * HH);
        __builtin_amdgcn_s_setprio(1);
#pragma unroll
        for (int kt = 0; kt < 4; ++kt) {
            if (kt < 3) {
                bnxt[0] = *(const bf16x8*)(B2 + (kt + 1) * 32);
                bnxt[1] = *(const bf16x8*)(B2 + 16 * HH + (kt + 1) * 32);
            }
            bf16x8 af[8];
#pragma unroll
            for (int rt = 0; rt < 8; ++rt) {
                const int row = rt * 16 + l15;
                af[rt] = *(const bf16x8*)(shAc + row * 256 + (((kt * 4 + l4) * 16) ^ ((row & 7) << 4)));
            }
#pragma unroll
            for (int rt = 0; rt < 8; ++rt) {
                acc[rt][0] = __builtin_amdgcn_mfma_f32_16x16x32_bf16(af[rt], bcur[0], acc[rt][0], 0, 0, 0);
                acc[rt][1] = __builtin_amdgcn_mfma_f32_16x16x32_bf16(af[rt], bcur[1], acc[rt][1], 0, 0, 0);
            }
            bcur[0] = bnxt[0];
            bcur[1] = bnxt[1];
        }
        __builtin_amdgcn_s_setprio(0);
    }
    __syncthreads();  // GEMM2 A-reads done before m overwrites shAc

    // epilogue: m = silu(acc+eb2)*em -> shAc; agg in-wave for both nodes
#pragma unroll
    for (int ct2 = 0; ct2 < 2; ++ct2) {
        const int c = c0 + ct2 * 16 + l15;
        const float b = shEb2[c];
        float paggA = 0.0f, paggB = 0.0f;
#pragma unroll
        for (int rt = 0; rt < 8; ++rt) {
            const int rbase = rt * 16 + l4 * 4;
            float v[4];
#pragma unroll
            for (int reg = 0; reg < 4; ++reg) {
                const int row = rbase + reg;
                const float emv = (rt < 4) ? shemA[row] : shemB[row - 64];
                v[reg] = silu_f(acc[rt][ct2][reg] + b) * emv;
                if (rt < 4) paggA += v[reg]; else paggB += v[reg];
            }
            const unsigned wlo = cvt_pk2(v[0], v[1]);
            const unsigned whi = cvt_pk2(v[2], v[3]);
            const int cx = c * 2;
#pragma unroll
            for (int reg = 0; reg < 4; ++reg) {
                const int row = rbase + reg;
                const unsigned wv = (reg < 2) ? wlo : whi;
                const short sv = (reg & 1) ? (short)(wv >> 16) : (short)(wv & 0xffff);
                *(short*)(shAc + row * 256 + (cx ^ ((row & 7) << 4))) = sv;
            }
        }
        paggA += __shfl_xor(paggA, 16);
        paggA += __shfl_xor(paggA, 32);
        paggB += __shfl_xor(paggB, 16);
        paggB += __shfl_xor(paggB, 32);
        if (l4 == 0) {
            agg[rA * HH + c] = paggA;
            agg[rB * HH + c] = paggB;
        }
    }
    __syncthreads();  // m complete before GEMM3 A reads

    // ---- GEMM3: c1 = m @ cw1 (col-sliced) ----
#pragma unroll
    for (int rt = 0; rt < 8; ++rt) {
        acc[rt][0] = (f32x4){0.f, 0.f, 0.f, 0.f};
        acc[rt][1] = (f32x4){0.f, 0.f, 0.f, 0.f};
    }
    {
        const short* B3 = cw1T + (size_t)(c0 + l15) * HH + l4 * 8;
        bf16x8 bcur[2], bnxt[2];
        bcur[0] = *(const bf16x8*)(B3);
        bcur[1] = *(const bf16x8*)(B3 + 16 * HH);
        __builtin_amdgcn_s_setprio(1);
#pragma unroll
        for (int kt = 0; kt < 4; ++kt) {
            if (kt < 3) {
                bnxt[0] = *(const bf16x8*)(B3 + (kt + 1) * 32);
                bnxt[1] = *(const bf16x8*)(B3 + 16 * HH + (kt + 1) * 32);
            }
            bf16x8 af[8];
#pragma unroll
            for (int rt = 0; rt < 8; ++rt) {
                const int row = rt * 16 + l15;
                af[rt] = *(const bf16x8*)(shAc + row * 256 + (((kt * 4 + l4) * 16) ^ ((row & 7) << 4)));
            }
#pragma unroll
            for (int rt = 0; rt < 8; ++rt) {
                acc[rt][0] = __builtin_amdgcn_mfma_f32_16x16x32_bf16(af[rt], bcur[0], acc[rt][0], 0, 0, 0);
                acc[rt][1] = __builtin_amdgcn_mfma_f32_16x16x32_bf16(af[rt], bcur[1], acc[rt][1], 0, 0, 0);
            }
            bcur[0] = bnxt[0];
            bcur[1] = bnxt[1];
        }
        __builtin_amdgcn_s_setprio(0);
    }

    // epilogue: phi partials, reduce over l15 within wave
    float pp[8][4];
    {
#pragma unroll
        for (int rt = 0; rt < 8; ++rt)
#pragma unroll
            for (int reg = 0; reg < 4; ++reg) pp[rt][reg] = 0.0f;
#pragma unroll
        for (int ct2 = 0; ct2 < 2; ++ct2) {
            const int c = c0 + ct2 * 16 + l15;
            const float cb = shCb1[c], cw = shCw2[c];
#pragma unroll
            for (int rt = 0; rt < 8; ++rt) {
#pragma unroll
                for (int reg = 0; reg < 4; ++reg) {
                    float v = silu_f(acc[rt][ct2][reg] + cb);
                    pp[rt][reg] = fmaf(v, cw, pp[rt][reg]);
                }
            }
        }
#pragma unroll
        for (int off = 8; off >= 1; off >>= 1) {
#pragma unroll
            for (int rt = 0; rt < 8; ++rt)
#pragma unroll
                for (int reg = 0; reg < 4; ++reg) pp[rt][reg] += __shfl_xor(pp[rt][reg], off);
        }
    }
    __syncthreads();  // ALL GEMM3 shAc reads done -> shphiP overlay safe
    if (l15 == 0) {
#pragma unroll
        for (int rt = 0; rt < 8; ++rt)
#pragma unroll
            for (int reg = 0; reg < 4; ++reg)
                shphiP[w * 128 + rt * 16 + l4 * 4 + reg] = pp[rt][reg];
    }
    __syncthreads();

    // x_out for both nodes (3 waves, one per coord; two sequential reductions)
    if (t < 192) {
        const int q = t >> 6, j = t & 63;
        float phiA = shphiP[0 * 128 + j] + shphiP[1 * 128 + j] + shphiP[2 * 128 + j] + shphiP[3 * 128 + j];
        float vA = shcdnA[j * 3 + q] * phiA * shemA[j];
        float phiB = shphiP[0 * 128 + 64 + j] + shphiP[1 * 128 + 64 + j] + shphiP[2 * 128 + 64 + j] + shphiP[3 * 128 + 64 + j];
        float vB = shcdnB[j * 3 + q] * phiB * shemB[j];
#pragma unroll
        for (int off = 32; off >= 1; off >>= 1) {
            vA += __shfl_xor(vA, off);
            vB += __shfl_xor(vB, off);
        }
        if (j == 0) {
            x_out[rA * 3 + q] = shx[iA * 3 + q] + vA;
            x_out[rB * 3 + q] = shx[iB * 3 + q] + vB;
        }
    }
}

// ---------------- fused: node update (in place) + NEXT layer's P,Q ----------------
// grid 256, XCD swizzle: g = bid&63, quarter = bid>>6 -> writer XCD == reader XCD.
__global__ __launch_bounds__(256) void nodepq_kernel(
    float* __restrict__ h, const float* __restrict__ agg, const float* __restrict__ nm,
    const short* __restrict__ nw1Tl, const float* __restrict__ nb1l,
    const short* __restrict__ nw2Tl, const float* __restrict__ nb2l,
    const short* __restrict__ ew1Tn, const float* __restrict__ eb1n,  // next layer
    float* __restrict__ P, float* __restrict__ Q, int do_pq) {
    const int g0n = (blockIdx.x & 63) * NN + (blockIdx.x >> 6) * 16;
    const int t = threadIdx.x;
    const int w = t >> 6, l = t & 63, l15 = l & 15, l4 = l >> 4;
    __shared__ __align__(16) char shN[16 * 512];  // [16 rows][256 bf16] = [h|agg], swizzled
    __shared__ __align__(16) char shT[16 * 256];  // [16 rows][128 bf16], swizzled
    char* shH = shN;  // reuse (dead after first GEMM) for new-h staging [16][128]

    {
        const int row = t >> 4, k0 = (t & 15) * 16;
        const float* src = (k0 < HH) ? (h + (size_t)(g0n + row) * HH + k0)
                                     : (agg + (size_t)(g0n + row) * HH + (k0 - HH));
        const float4 a = *(const float4*)src;
        const float4 b = *(const float4*)(src + 4);
        const float4 c = *(const float4*)(src + 8);
        const float4 d = *(const float4*)(src + 12);
        uint32x4 s0, s1;
        s0[0] = cvt_pk2(a.x, a.y); s0[1] = cvt_pk2(a.z, a.w);
        s0[2] = cvt_pk2(b.x, b.y); s0[3] = cvt_pk2(b.z, b.w);
        s1[0] = cvt_pk2(c.x, c.y); s1[1] = cvt_pk2(c.z, c.w);
        s1[2] = cvt_pk2(d.x, d.y); s1[3] = cvt_pk2(d.z, d.w);
        const int xr = (row & 7) << 4;
        *(uint32x4*)(shN + row * 512 + ((k0 * 2) ^ xr)) = s0;
        *(uint32x4*)(shN + row * 512 + ((k0 * 2 + 16) ^ xr)) = s1;
    }
    __syncthreads();

    const int c0 = w * 32;
    f32x4 acc[2];
    acc[0] = (f32x4){0.f, 0.f, 0.f, 0.f};
    acc[1] = (f32x4){0.f, 0.f, 0.f, 0.f};
#pragma unroll
    for (int kt = 0; kt < 8; ++kt) {
        const bf16x8 af = *(const bf16x8*)(shN + l15 * 512 + (((kt * 4 + l4) * 16) ^ ((l15 & 7) << 4)));
#pragma unroll
        for (int ct2 = 0; ct2 < 2; ++ct2) {
            const bf16x8 bf = *(const bf16x8*)(nw1Tl + (size_t)(c0 + ct2 * 16 + l15) * 256 + kt * 32 + l4 * 8);
            acc[ct2] = __builtin_amdgcn_mfma_f32_16x16x32_bf16(af, bf, acc[ct2], 0, 0, 0);
        }
    }
    __syncthreads();  // all shN reads done (shH overwrite below must not race)
#pragma unroll
    for (int ct2 = 0; ct2 < 2; ++ct2) {
        const int c = c0 + ct2 * 16 + l15;
        const float b = nb1l[c];
        float v[4];
#pragma unroll
        for (int reg = 0; reg < 4; ++reg) v[reg] = silu_f(acc[ct2][reg] + b);
        const unsigned wlo = cvt_pk2(v[0], v[1]);
        const unsigned whi = cvt_pk2(v[2], v[3]);
#pragma unroll
        for (int reg = 0; reg < 4; ++reg) {
            const int row = l4 * 4 + reg;
            const unsigned wv = (reg < 2) ? wlo : whi;
            const short sv = (reg & 1) ? (short)(wv >> 16) : (short)(wv & 0xffff);
            *(short*)(shT + row * 256 + ((c * 2) ^ ((row & 7) << 4))) = sv;
        }
    }
    __syncthreads();

    acc[0] = (f32x4){0.f, 0.f, 0.f, 0.f};
    acc[1] = (f32x4){0.f, 0.f, 0.f, 0.f};
#pragma unroll
    for (int kt = 0; kt < 4; ++kt) {
        const bf16x8 af = *(const bf16x8*)(shT + l15 * 256 + (((kt * 4 + l4) * 16) ^ ((l15 & 7) << 4)));
#pragma unroll
        for (int ct2 = 0; ct2 < 2; ++ct2) {
            const bf16x8 bf = *(const bf16x8*)(nw2Tl + (size_t)(c0 + ct2 * 16 + l15) * HH + kt * 32 + l4 * 8);
            acc[ct2] = __builtin_amdgcn_mfma_f32_16x16x32_bf16(af, bf, acc[ct2], 0, 0, 0);
        }
    }
    // h' = (h + mlp + b)*nm : write global, stage bf16 into shH for pq
    float hn[2][4];
#pragma unroll
    for (int ct2 = 0; ct2 < 2; ++ct2) {
        const int c = c0 + ct2 * 16 + l15;
        const float b = nb2l[c];
#pragma unroll
        for (int reg = 0; reg < 4; ++reg) {
            const int n = g0n + l4 * 4 + reg;
            const float hv = h[(size_t)n * HH + c];
            hn[ct2][reg] = (hv + acc[ct2][reg] + b) * nm[n];
            h[(size_t)n * HH + c] = hn[ct2][reg];
        }
    }
    if (!do_pq) return;

#pragma unroll
    for (int ct2 = 0; ct2 < 2; ++ct2) {
        const int c = c0 + ct2 * 16 + l15;
        const unsigned wlo = cvt_pk2(hn[ct2][0], hn[ct2][1]);
        const unsigned whi = cvt_pk2(hn[ct2][2], hn[ct2][3]);
#pragma unroll
        for (int reg = 0; reg < 4; ++reg) {
            const int row = l4 * 4 + reg;
            const unsigned wv = (reg < 2) ? wlo : whi;
            const short sv = (reg & 1) ? (short)(wv >> 16) : (short)(wv & 0xffff);
            *(short*)(shH + row * 256 + ((c * 2) ^ ((row & 7) << 4))) = sv;
        }
    }
    __syncthreads();

    // pq GEMM: 256 output cols; wave w covers c' = half*128 + [c0, c0+32)
    f32x4 pacc[2][2];
#pragma unroll
    for (int half = 0; half < 2; ++half) {
        pacc[half][0] = (f32x4){0.f, 0.f, 0.f, 0.f};
        pacc[half][1] = (f32x4){0.f, 0.f, 0.f, 0.f};
    }
#pragma unroll
    for (int kt = 0; kt < 4; ++kt) {
        const bf16x8 af = *(const bf16x8*)(shH + l15 * 256 + (((kt * 4 + l4) * 16) ^ ((l15 & 7) << 4)));
#pragma unroll
        for (int half = 0; half < 2; ++half) {
#pragma unroll
            for (int ct2 = 0; ct2 < 2; ++ct2) {
                const bf16x8 bf = *(const bf16x8*)(ew1Tn + (size_t)(half * 128 + c0 + ct2 * 16 + l15) * HH + kt * 32 + l4 * 8);
                pacc[half][ct2] = __builtin_amdgcn_mfma_f32_16x16x32_bf16(af, bf, pacc[half][ct2], 0, 0, 0);
            }
        }
    }
#pragma unroll
    for (int half = 0; half < 2; ++half) {
#pragma unroll
        for (int ct2 = 0; ct2 < 2; ++ct2) {
            const int cp = half * 128 + c0 + ct2 * 16 + l15;
            const int c = cp & 127;
            float* dst = (cp >= HH) ? Q : P;
            const float bias = (cp >= HH) ? 0.0f : eb1n[c];
#pragma unroll
            for (int reg = 0; reg < 4; ++reg) {
                const int n = g0n + l4 * 4 + reg;
                dst[(size_t)n * HH + c] = pacc[half][ct2][reg] + bias;
            }
        }
    }
}

// ---------------- output: per-graph mean of (h@out_w + out_b)*nm ----------------
__global__ void out_kernel(const float* __restrict__ h, const float* __restrict__ nm,
                           const float* __restrict__ ow, const float* __restrict__ ob,
                           float* __restrict__ out) {
    const int b = blockIdx.x;
    const int n = threadIdx.x;  // 64
    const int v = b * NN + n;
    float acc = 0.0f;
#pragma unroll 8
    for (int c = 0; c < HH; ++c) acc = fmaf(h[v * HH + c], ow[c], acc);
    acc = (acc + ob[0]) * nm[v];
#pragma unroll
    for (int off = 32; off >= 1; off >>= 1) acc += __shfl_xor(acc, off);
    if (n == 0) out[b] = acc * (1.0f / (float)NN);
}

extern "C" void kernel_launch(void* const* d_in, const int* in_sizes, int n_in,
                              void* d_out, int out_size, void* d_ws, size_t ws_size,
                              hipStream_t stream) {
    const float* xh    = (const float*)d_in[0];
    const float* nmask = (const float*)d_in[1];
    const float* emask = (const float*)d_in[2];
    const float* emb_w = (const float*)d_in[3];
    const float* emb_b = (const float*)d_in[4];
    const float* out_w = (const float*)d_in[5];
    const float* out_b = (const float*)d_in[6];
    const float* ew1   = (const float*)d_in[7];
    const float* eb1   = (const float*)d_in[8];
    const float* ew2   = (const float*)d_in[9];
    const float* eb2   = (const float*)d_in[10];
    const float* nw1   = (const float*)d_in[11];
    const float* nb1   = (const float*)d_in[12];
    const float* nw2   = (const float*)d_in[13];
    const float* nb2   = (const float*)d_in[14];
    const float* cw1   = (const float*)d_in[15];
    const float* cb1   = (const float*)d_in[16];
    const float* cw2   = (const float*)d_in[17];

    float* ws  = (float*)d_ws;
    float* xA  = ws;                    // [4096*3]
    float* xB  = xA + BNODES * 3;       // [4096*3]
    float* x0  = xB + BNODES * 3;       // [4096*3]
    float* h   = x0 + BNODES * 3;       // [4096*128]
    float* Pb  = h + BNODES * HH;       // [4096*128]
    float* Qb  = Pb + BNODES * HH;      // [4096*128]
    float* agg = Qb + BNODES * HH;      // [4096*128]
    short* ew2T = (short*)(agg + BNODES * HH);  // [4][128*128] bf16
    short* cw1T = ew2T + LL * HH * HH;          // [4][128*128] bf16
    short* ew1T = cw1T + LL * HH * HH;          // [4][256*128] bf16
    short* nw1T = ew1T + LL * 256 * HH;         // [4][128*256] bf16
    short* nw2T = nw1T + LL * 256 * HH;         // [4][128*128] bf16

    prep_kernel<<<BNODES, HH, 0, stream>>>(xh, nmask, emb_w, emb_b, xA, x0, h);
    wprep_kernel<<<5 * LL, 256, 0, stream>>>(ew1, ew2, cw1, nw1, nw2,
                                             ew1T, ew2T, cw1T, nw1T, nw2T);

    pq_kernel<<<512, 256, 0, stream>>>(h, ew1T, eb1, Pb, Qb);

    float* xc = xA;
    float* xn = xB;
    for (int l = 0; l < LL; ++l) {
        const float* ew1l = ew1 + (size_t)l * 258 * HH;
        edge_kernel<<<BNODES / 2, 256, 0, stream>>>(Pb, Qb, xc, x0, emask, ew1l,
                                                    ew2T + (size_t)l * HH * HH, eb2 + l * HH,
                                                    cw1T + (size_t)l * HH * HH, cb1 + l * HH,
                                                    cw2 + (size_t)l * HH, xn, agg);
        const int do_pq = (l + 1 < LL) ? 1 : 0;
        const int ln = do_pq ? (l + 1) : 0;
        nodepq_kernel<<<256, 256, 0, stream>>>(h, agg, nmask,
                                               nw1T + (size_t)l * 2 * HH * HH, nb1 + l * HH,
                                               nw2T + (size_t)l * HH * HH, nb2 + l * HH,
                                               ew1T + (size_t)ln * 256 * HH, eb1 + ln * HH,
                                               Pb, Qb, do_pq);
        float* tmp = xc; xc = xn; xn = tmp;
    }

    out_kernel<<<NB, NN, 0, stream>>>(h, nmask, out_w, out_b, (float*)d_out);
}